// Round 6
// baseline (309.588 us; speedup 1.0000x reference)
//
#include <hip/hip_runtime.h>
#include <hip/hip_bf16.h>
#include <stdint.h>

// Problem constants
#define BB     8
#define CC     128
#define HW     9216      // 96*96
#define NHEAD  8
#define HD     64
#define NCH    16        // gram n-chunks
#define CHUNK  576       // HW/NCH

typedef __hip_bfloat16 bf16;
using frag16 = __attribute__((ext_vector_type(8))) short;  // 8 bf16 (4 VGPRs)
using f32x4  = __attribute__((ext_vector_type(4))) float;

__device__ __forceinline__ float b2f(bf16 v) { return __bfloat162float(v); }
__device__ __forceinline__ bf16  f2b(float v) { return __float2bfloat16(v); }
__device__ __forceinline__ float us2f(unsigned short u) {
  return __uint_as_float(((unsigned int)u) << 16);
}
__device__ __forceinline__ unsigned short f2us(float v) {
  bf16 h = f2b(v);
  return *(unsigned short*)&h;
}

// ---------------------------------------------------------------- K1: qkv depthwise conv + q/k norm partials
// block = (tile, b*128+c); tile = 32 rows of the 96-row plane. LDS = 34x104 fp32 halo (14.2 KB)
// -> ~6 blocks/CU occupancy (vs 2 with full-plane staging).
// conv out channel oc = c*12 + j; j in [0,4)=q(e=j), [4,8)=k, [8,12)=v.
// head h = e*2 + c/64, row d = c%64. Stores q,k,v bf16 as [b, h, d_or_e, n].
// Norm ssq partials per tile -> qn2p/kn2p[3][4096], summed in k2_softmax.
__global__ __launch_bounds__(256) void k1_qkv(
    const float* __restrict__ x, const float* __restrict__ wq,
    const float* __restrict__ bq,
    bf16* __restrict__ qg, bf16* __restrict__ kg, bf16* __restrict__ vg,
    float* __restrict__ qn2p, float* __restrict__ kn2p) {
  __shared__ float xs[34 * 104];    // 14.1 KB zero-padded halo; interior col base 4
  __shared__ float red[32];
  int tid = threadIdx.x;
  int wave = tid >> 6, lane = tid & 63;
  int tile = blockIdx.x;            // 0..2
  int bc = blockIdx.y;
  int b = bc >> 7, c = bc & 127;
  const float* xp = x + (size_t)(b * CC + c) * HW;
  // zero all (covers halo), then fill in-range rows
  for (int i = tid; i < (34 * 104) / 4; i += 256)
    ((float4*)xs)[i] = make_float4(0.f, 0.f, 0.f, 0.f);
  __syncthreads();
  int gr0 = tile * 32 - 1;          // global row of xs row 0
  for (int i = tid; i < 34 * 24; i += 256) {
    int rr = i / 24, g4 = i - rr * 24;
    int gr = gr0 + rr;
    if (gr >= 0 && gr < 96)
      ((float4*)(xs + rr * 104 + 4))[g4] = ((const float4*)(xp + gr * 96))[g4];
  }
  __syncthreads();

  int half = c >> 6, d = c & 63;
  int nidx[8];
  size_t basep[12];
#pragma unroll
  for (int j = 0; j < 12; ++j) {
    int e = j & 3;                       // j%4 within each q/k/v group
    int h = e * 2 + half;
    int ni = (b * NHEAD + h) * HD + d;
    if (j < 8) nidx[j] = ni;
    basep[j] = (size_t)ni * HW;
  }
  const float* wrow = wq + c * 108;      // 12 channels * 9 taps, uniform -> s_load
  const float* brow = bq + c * 12;

  float ssq[8];
#pragma unroll
  for (int j = 0; j < 8; ++j) ssq[j] = 0.f;

#pragma unroll 1
  for (int it = 0; it < 3; ++it) {
    int q4i = it * 256 + tid;            // 0..767 : 32 rows * 24 groups
    int ly = q4i / 24;                   // local row 0..31
    int xx = (q4i - ly * 24) * 4;
    int p0 = (tile * 32 + ly) * 96 + xx;
    // 3 rows x 6 cols into registers (xs row ly+ky == global row tile*32+ly+ky-1)
    float w6[3][6];
#pragma unroll
    for (int ky = 0; ky < 3; ++ky) {
      int basea = (ly + ky) * 104 + 4 + xx;   // 16B-aligned
      float4 M = *(const float4*)&xs[basea];
      w6[ky][0] = xs[basea - 1];
      w6[ky][1] = M.x; w6[ky][2] = M.y; w6[ky][3] = M.z; w6[ky][4] = M.w;
      w6[ky][5] = xs[basea + 4];
    }
#pragma unroll
    for (int j = 0; j < 12; ++j) {
      float bias = brow[j];
      float a0 = bias, a1 = bias, a2 = bias, a3 = bias;
#pragma unroll
      for (int ky = 0; ky < 3; ++ky)
#pragma unroll
        for (int kx = 0; kx < 3; ++kx) {
          float w = wrow[j * 9 + ky * 3 + kx];
          a0 = fmaf(w, w6[ky][kx + 0], a0);
          a1 = fmaf(w, w6[ky][kx + 1], a1);
          a2 = fmaf(w, w6[ky][kx + 2], a2);
          a3 = fmaf(w, w6[ky][kx + 3], a3);
        }
      ushort4 st;
      st.x = f2us(a0); st.y = f2us(a1); st.z = f2us(a2); st.w = f2us(a3);
      if (j < 4)      *(ushort4*)(qg + basep[j] + p0) = st;
      else if (j < 8) *(ushort4*)(kg + basep[j] + p0) = st;
      else            *(ushort4*)(vg + basep[j] + p0) = st;
      if (j < 8) {
        float v0 = us2f(st.x), v1 = us2f(st.y), v2 = us2f(st.z), v3 = us2f(st.w);
        ssq[j] += v0 * v0 + v1 * v1 + v2 * v2 + v3 * v3;
      }
    }
  }
  // wave shuffle-reduce the 8 sums, then one LDS combine across the 4 waves
#pragma unroll
  for (int j = 0; j < 8; ++j) {
    float v = ssq[j];
#pragma unroll
    for (int off = 32; off > 0; off >>= 1) v += __shfl_down(v, off);
    if (lane == 0) red[wave * 8 + j] = v;
  }
  __syncthreads();
  if (tid < 8) {
    float s = red[tid] + red[8 + tid] + red[16 + tid] + red[24 + tid];
    if (tid < 4) qn2p[tile * 4096 + nidx[tid]] = s;
    else         kn2p[tile * 4096 + nidx[tid]] = s;
  }
}

// ---------------------------------------------------------------- K2a: gram partials via MFMA
// part[bh][chunk][d][e] += q[d][n]*k[e][n] over the chunk. A=qg rows, B^T=kg rows.
__global__ __launch_bounds__(256) void k2_gram(
    const bf16* __restrict__ qg, const bf16* __restrict__ kg,
    float* __restrict__ part) {
  int tid = threadIdx.x;
  int wave = tid >> 6;           // 0..3 -> d-tile
  int lane = tid & 63;
  int chunk = blockIdx.x;        // 0..15
  int bh = blockIdx.y;           // 0..63
  const size_t base = (size_t)bh * HD * HW;
  int m = lane & 15;
  int k8 = (lane >> 4) * 8;
  const bf16* qrow  = qg + base + (size_t)(wave * 16 + m) * HW + k8;
  const bf16* krow0 = kg + base + (size_t)m * HW + k8;
  f32x4 acc0 = {0.f, 0.f, 0.f, 0.f}, acc1 = acc0, acc2 = acc0, acc3 = acc0;
  for (int kb = 0; kb < CHUNK; kb += 32) {
    int off = chunk * CHUNK + kb;
    frag16 a  = *(const frag16*)(qrow + off);
    frag16 b0 = *(const frag16*)(krow0 + off);
    frag16 b1 = *(const frag16*)(krow0 + (size_t)16 * HW + off);
    frag16 b2 = *(const frag16*)(krow0 + (size_t)32 * HW + off);
    frag16 b3 = *(const frag16*)(krow0 + (size_t)48 * HW + off);
    acc0 = __builtin_amdgcn_mfma_f32_16x16x32_bf16(a, b0, acc0, 0, 0, 0);
    acc1 = __builtin_amdgcn_mfma_f32_16x16x32_bf16(a, b1, acc1, 0, 0, 0);
    acc2 = __builtin_amdgcn_mfma_f32_16x16x32_bf16(a, b2, acc2, 0, 0, 0);
    acc3 = __builtin_amdgcn_mfma_f32_16x16x32_bf16(a, b3, acc3, 0, 0, 0);
  }
  // C/D layout: row(d) = (lane>>4)*4 + r, col(e) = lane&15
  float* po = part + (size_t)(bh * NCH + chunk) * 4096;
  int dr = wave * 16 + (lane >> 4) * 4;
  int e0 = lane & 15;
#pragma unroll
  for (int r = 0; r < 4; ++r) {
    po[(dr + r) * 64 +  0 + e0] = acc0[r];
    po[(dr + r) * 64 + 16 + e0] = acc1[r];
    po[(dr + r) * 64 + 32 + e0] = acc2[r];
    po[(dr + r) * 64 + 48 + e0] = acc3[r];
  }
}

// ---------------------------------------------------------------- K2r: reduce partials -> gram
__global__ void k2_reduce(const float* __restrict__ part, float* __restrict__ gram) {
  int idx = blockIdx.x * 256 + threadIdx.x;   // < 64*4096
  int bh = idx >> 12, de = idx & 4095;
  float s = 0.f;
#pragma unroll
  for (int ch = 0; ch < NCH; ++ch)
    s += part[(size_t)(bh * NCH + ch) * 4096 + de];
  gram[idx] = s;
}

// ---------------------------------------------------------------- K2b: normalize + softmax
// attn row-major [d][e], emitted as bf16 hi/lo split: hi+lo ~= attn to ~2^-17.
__global__ __launch_bounds__(64) void k2_softmax(
    const float* __restrict__ gram, bf16* __restrict__ ah, bf16* __restrict__ al,
    const float* __restrict__ qn2p, const float* __restrict__ kn2p,
    const float* __restrict__ t_f) {
  __shared__ float kns[64];
  int bh = blockIdx.x, d = threadIdx.x;
  const size_t base = (size_t)bh * 4096;
  int ni = bh * 64 + d;
  kns[d] = fmaxf(sqrtf(kn2p[ni] + kn2p[4096 + ni] + kn2p[8192 + ni]), 1e-12f);
  __syncthreads();
  float qn = fmaxf(sqrtf(qn2p[ni] + qn2p[4096 + ni] + qn2p[8192 + ni]), 1e-12f);
  float sc = t_f[bh & 7] / qn;
  float lg[64];
  float m = -1e30f;
#pragma unroll
  for (int e = 0; e < 64; ++e) {
    lg[e] = gram[base + d * 64 + e] * sc / kns[e];
    m = fmaxf(m, lg[e]);
  }
  float s = 0.f;
#pragma unroll
  for (int e = 0; e < 64; ++e) { lg[e] = __expf(lg[e] - m); s += lg[e]; }
  float inv = 1.f / s;
#pragma unroll
  for (int e = 0; e < 64; ++e) {
    float p = lg[e] * inv;
    bf16 hi = f2b(p);
    ah[base + d * 64 + e] = hi;
    al[base + d * 64 + e] = f2b(p - b2f(hi));
  }
}

// ---------------------------------------------------------------- K3: o = attn @ v via MFMA
// block = (chunk of 256 px, bh). v tile staged in LDS [64 e][260 pad] bf16.
__global__ __launch_bounds__(256) void k3_av(
    const bf16* __restrict__ ah, const bf16* __restrict__ al,
    const bf16* __restrict__ vg, bf16* __restrict__ og) {
  __shared__ unsigned short vs[64 * 260];   // 33.3 KB
  int tid = threadIdx.x;
  int wave = tid >> 6, lane = tid & 63;
  int chunk = blockIdx.x;   // 0..35 (256 pixels each)
  int bh = blockIdx.y;      // 0..63
  int b = bh >> 3, h = bh & 7;
  int n0 = chunk * 256;
  const bf16* vp = vg + (size_t)bh * HD * HW;
#pragma unroll
  for (int i = 0; i < 16; ++i) {
    int lin = i * 256 + tid;            // ushort4 units: 64 rows * 64 units
    int e = lin >> 6, c4 = lin & 63;
    ushort4 vv = *(const ushort4*)(vp + (size_t)e * HW + n0 + c4 * 4);
    *(ushort4*)&vs[e * 260 + c4 * 4] = vv;
  }
  __syncthreads();

  int m = lane & 15;
  int k8 = (lane >> 4) * 8;
  const bf16* ahp = ah + (size_t)bh * 4096;
  const bf16* alp = al + (size_t)bh * 4096;
  frag16 a_hi[4][2], a_lo[4][2];
#pragma unroll
  for (int dt = 0; dt < 4; ++dt)
#pragma unroll
    for (int kh = 0; kh < 2; ++kh) {
      a_hi[dt][kh] = *(const frag16*)(ahp + (dt * 16 + m) * 64 + kh * 32 + k8);
      a_lo[dt][kh] = *(const frag16*)(alp + (dt * 16 + m) * 64 + kh * 32 + k8);
    }

  f32x4 acc[4][4];
#pragma unroll
  for (int dt = 0; dt < 4; ++dt)
#pragma unroll
    for (int nt = 0; nt < 4; ++nt) acc[dt][nt] = {0.f, 0.f, 0.f, 0.f};

  int nwbase = wave * 64;
#pragma unroll
  for (int nt = 0; nt < 4; ++nt) {
#pragma unroll
    for (int kh = 0; kh < 2; ++kh) {
      frag16 bf;
#pragma unroll
      for (int j = 0; j < 8; ++j)
        bf[j] = (short)vs[(kh * 32 + k8 + j) * 260 + nwbase + nt * 16 + m];
#pragma unroll
      for (int dt = 0; dt < 4; ++dt) {
        acc[dt][nt] = __builtin_amdgcn_mfma_f32_16x16x32_bf16(a_hi[dt][kh], bf, acc[dt][nt], 0, 0, 0);
        acc[dt][nt] = __builtin_amdgcn_mfma_f32_16x16x32_bf16(a_lo[dt][kh], bf, acc[dt][nt], 0, 0, 0);
      }
    }
  }
  int cc0 = (h & 1) * 256 + (h >> 1);
  bf16* ob = og + (size_t)b * 512 * HW;
  int q4 = (lane >> 4) * 4;
#pragma unroll
  for (int dt = 0; dt < 4; ++dt)
#pragma unroll
    for (int nt = 0; nt < 4; ++nt) {
      int n = n0 + nwbase + nt * 16 + m;
#pragma unroll
      for (int r = 0; r < 4; ++r) {
        int d = dt * 16 + q4 + r;
        ob[(size_t)(cc0 + d * 4) * HW + n] = f2b(acc[dt][nt][r]);
      }
    }
}

// ---------------------------------------------------------------- K4: fused grouped 3x3 conv (4 in-ch -> 1 out-ch)
__global__ __launch_bounds__(256) void k4_fuse(
    const bf16* __restrict__ og, const float* __restrict__ wf,
    const float* __restrict__ bfu, float* __restrict__ out) {
  __shared__ float lds[26 * 100 * 4];   // 41.6 KB
  int tid = threadIdx.x;
  int tile = blockIdx.x;                // 0..3
  int bc = blockIdx.y;                  // 0..1023
  int b = bc >> 7, c = bc & 127;
  for (int i = tid; i < (26 * 100 * 4) / 4; i += 256)
    ((float4*)lds)[i] = make_float4(0.f, 0.f, 0.f, 0.f);
  __syncthreads();
  int r0 = tile * 24 - 1;
  const bf16* op = og + (size_t)(b * 512 + c * 4) * HW;
  for (int i = tid; i < 26 * 96; i += 256) {
    int rr = i / 96, x = i - rr * 96;
    int gr = r0 + rr;
    if (gr >= 0 && gr < 96) {
      int gp = gr * 96 + x;
      float4 vv;
      vv.x = b2f(op[gp]);
      vv.y = b2f(op[HW + gp]);
      vv.z = b2f(op[2 * HW + gp]);
      vv.w = b2f(op[(size_t)3 * HW + gp]);
      *(float4*)&lds[(rr * 100 + 2 + x) * 4] = vv;
    }
  }
  __syncthreads();
  const float* wrow = wf + c * 36;      // uniform -> s_load
  float bias = bfu[c];
  float* outp = out + (size_t)(b * CC + c) * HW + tile * 24 * 96;
#pragma unroll
  for (int pi = 0; pi < 9; ++pi) {
    int p = pi * 256 + tid;
    int ry = p / 96, x = p - ry * 96;
    float a0 = bias, a1 = 0.f, a2 = 0.f, a3 = 0.f;
#pragma unroll
    for (int ky = 0; ky < 3; ++ky)
#pragma unroll
      for (int kx = 0; kx < 3; ++kx) {
        const float4 vv = *(const float4*)&lds[((ry + ky) * 100 + 1 + x + kx) * 4];
        a0 = fmaf(wrow[0 + ky * 3 + kx],  vv.x, a0);
        a1 = fmaf(wrow[9 + ky * 3 + kx],  vv.y, a1);
        a2 = fmaf(wrow[18 + ky * 3 + kx], vv.z, a2);
        a3 = fmaf(wrow[27 + ky * 3 + kx], vv.w, a3);
      }
    outp[p] = (a0 + a1) + (a2 + a3);
  }
}

// ---------------------------------------------------------------- launcher
extern "C" void kernel_launch(void* const* d_in, const int* in_sizes, int n_in,
                              void* d_out, int out_size, void* d_ws, size_t ws_size,
                              hipStream_t stream) {
  (void)in_sizes; (void)n_in; (void)out_size; (void)ws_size;
  const float* x   = (const float*)d_in[0];
  const float* wq  = (const float*)d_in[1];
  const float* bq  = (const float*)d_in[2];
  const float* tt  = (const float*)d_in[3];
  const float* wf  = (const float*)d_in[4];
  const float* bfu = (const float*)d_in[5];

  // workspace layout (~246 MB)
  char* ws = (char*)d_ws;
  bf16*  qg    = (bf16*)(ws + 0);                 // 75497472 B, later aliased by og
  bf16*  kg    = (bf16*)(ws + 75497472);          // 75497472 B
  bf16*  vg    = (bf16*)(ws + 150994944);         // 75497472 B
  float* part  = (float*)(ws + 226492416);        // 16777216 B
  float* gram  = (float*)(ws + 243269632);        // 1048576 B
  bf16*  ah    = (bf16*)(ws + 244318208);         // 524288 B
  bf16*  al    = (bf16*)(ws + 244842496);         // 524288 B
  float* qn2p  = (float*)(ws + 245366784);        // 49152 B (3 tiles x 4096)
  float* kn2p  = (float*)(ws + 245415936);        // 49152 B
  bf16*  og    = qg;                              // q is dead after k2_gram
  float* out   = (float*)d_out;

  hipLaunchKernelGGL(k1_qkv, dim3(3, 1024), dim3(256), 0, stream,
                     x, wq, bq, qg, kg, vg, qn2p, kn2p);
  hipLaunchKernelGGL(k2_gram, dim3(NCH, 64), dim3(256), 0, stream, qg, kg, part);
  hipLaunchKernelGGL(k2_reduce, dim3(1024), dim3(256), 0, stream, part, gram);
  hipLaunchKernelGGL(k2_softmax, dim3(64), dim3(64), 0, stream,
                     gram, ah, al, qn2p, kn2p, tt);
  hipLaunchKernelGGL(k3_av, dim3(36, 64), dim3(256), 0, stream, ah, al, vg, og);
  hipLaunchKernelGGL(k4_fuse, dim3(4, 1024), dim3(256), 0, stream, og, wf, bfu, out);
}

// Round 7
// 283.599 us; speedup vs baseline: 1.0916x; 1.0916x over previous
//
#include <hip/hip_runtime.h>
#include <hip/hip_bf16.h>
#include <stdint.h>

// Problem constants
#define BB     8
#define CC     128
#define HW     9216      // 96*96
#define NHEAD  8
#define HD     64
#define NCH    16        // gram n-chunks
#define CHUNK  576       // HW/NCH

typedef __hip_bfloat16 bf16;
using frag16 = __attribute__((ext_vector_type(8))) short;  // 8 bf16 (4 VGPRs)
using f32x4  = __attribute__((ext_vector_type(4))) float;

__device__ __forceinline__ float b2f(bf16 v) { return __bfloat162float(v); }
__device__ __forceinline__ bf16  f2b(float v) { return __float2bfloat16(v); }

__device__ __forceinline__ unsigned int pack2(float a, float b) {
  union { __hip_bfloat162 h2; unsigned int u; } c;
  c.h2 = __float22bfloat162_rn(make_float2(a, b));   // v_cvt_pk_bf16_f32
  return c.u;
}

// ---------------------------------------------------------------- K1: qkv depthwise conv + q/k norms
// block = (b, c), full 96x96 plane in zero-padded LDS (98 rows x stride 100, +4 pad; interior col base 4).
// conv out channel oc = c*12 + j; j in [0,4)=q(e=j), [4,8)=k, [8,12)=v.
// head h = e*2 + c/64, row d = c%64. Stores q,k,v bf16 as [b, h, d_or_e, n].
// 4 px/thread; packed cvt_pk_bf16 stores; ssq from pre-rounded fp32 (margin >> bf16 eps).
__global__ __launch_bounds__(256) void k1_qkv(
    const float* __restrict__ x, const float* __restrict__ wq,
    const float* __restrict__ bq,
    bf16* __restrict__ qg, bf16* __restrict__ kg, bf16* __restrict__ vg,
    float* __restrict__ qn2, float* __restrict__ kn2) {
  __shared__ float xs[98 * 100 + 4];  // 39.2 KB zero-padded halo; +4 guard for last-row read
  __shared__ float red[32];
  int tid = threadIdx.x;
  int wave = tid >> 6, lane = tid & 63;
  int b = blockIdx.x >> 7, c = blockIdx.x & 127;
  const float* xp = x + (size_t)(b * CC + c) * HW;
  for (int i = tid; i < (98 * 100 + 4) / 4; i += 256)
    ((float4*)xs)[i] = make_float4(0.f, 0.f, 0.f, 0.f);
  __syncthreads();
  for (int i = tid; i < 96 * 24; i += 256) {
    int y = i / 24, g4 = i - y * 24;
    ((float4*)(xs + (y + 1) * 100 + 4))[g4] = ((const float4*)(xp + y * 96))[g4];
  }
  __syncthreads();

  int half = c >> 6, d = c & 63;
  int nidx[8];
  size_t basep[12];
#pragma unroll
  for (int j = 0; j < 12; ++j) {
    int e = j & 3;                       // j%4 within each q/k/v group
    int h = e * 2 + half;
    int ni = (b * NHEAD + h) * HD + d;
    if (j < 8) nidx[j] = ni;
    basep[j] = (size_t)ni * HW;
  }
  const float* wrow = wq + c * 108;      // 12 channels * 9 taps, uniform -> s_load
  const float* brow = bq + c * 12;

  float ssq[8];
#pragma unroll
  for (int j = 0; j < 8; ++j) ssq[j] = 0.f;

#pragma unroll 1
  for (int it = 0; it < 9; ++it) {
    int q4i = it * 256 + tid;            // 0..2303
    int y = q4i / 24;                    // row 0..95
    int xx = (q4i - y * 24) * 4;
    int p0 = y * 96 + xx;
    float w6[3][6];
#pragma unroll
    for (int ky = 0; ky < 3; ++ky) {
      int basea = (y + ky) * 100 + 4 + xx;   // 16B-aligned
      float4 M = *(const float4*)&xs[basea];
      w6[ky][0] = xs[basea - 1];
      w6[ky][1] = M.x; w6[ky][2] = M.y; w6[ky][3] = M.z; w6[ky][4] = M.w;
      w6[ky][5] = xs[basea + 4];
    }
#pragma unroll
    for (int j = 0; j < 12; ++j) {
      float bias = brow[j];
      float a0 = bias, a1 = bias, a2 = bias, a3 = bias;
#pragma unroll
      for (int ky = 0; ky < 3; ++ky)
#pragma unroll
        for (int kx = 0; kx < 3; ++kx) {
          float w = wrow[j * 9 + ky * 3 + kx];
          a0 = fmaf(w, w6[ky][kx + 0], a0);
          a1 = fmaf(w, w6[ky][kx + 1], a1);
          a2 = fmaf(w, w6[ky][kx + 2], a2);
          a3 = fmaf(w, w6[ky][kx + 3], a3);
        }
      uint2 st = make_uint2(pack2(a0, a1), pack2(a2, a3));
      if (j < 4)      *(uint2*)(qg + basep[j] + p0) = st;
      else if (j < 8) *(uint2*)(kg + basep[j] + p0) = st;
      else            *(uint2*)(vg + basep[j] + p0) = st;
      if (j < 8)
        ssq[j] += a0 * a0 + a1 * a1 + a2 * a2 + a3 * a3;
    }
  }
  // wave shuffle-reduce the 8 sums, then one LDS combine across the 4 waves
#pragma unroll
  for (int j = 0; j < 8; ++j) {
    float v = ssq[j];
#pragma unroll
    for (int off = 32; off > 0; off >>= 1) v += __shfl_down(v, off);
    if (lane == 0) red[wave * 8 + j] = v;
  }
  __syncthreads();
  if (tid < 8) {
    float s = red[tid] + red[8 + tid] + red[16 + tid] + red[24 + tid];
    if (tid < 4) qn2[nidx[tid]] = s;
    else         kn2[nidx[tid]] = s;
  }
}

// ---------------------------------------------------------------- K2a: gram partials via MFMA
// part[bh][chunk][d][e] += q[d][n]*k[e][n] over the chunk. A=qg rows, B^T=kg rows.
__global__ __launch_bounds__(256) void k2_gram(
    const bf16* __restrict__ qg, const bf16* __restrict__ kg,
    float* __restrict__ part) {
  int tid = threadIdx.x;
  int wave = tid >> 6;           // 0..3 -> d-tile
  int lane = tid & 63;
  int chunk = blockIdx.x;        // 0..15
  int bh = blockIdx.y;           // 0..63
  const size_t base = (size_t)bh * HD * HW;
  int m = lane & 15;
  int k8 = (lane >> 4) * 8;
  const bf16* qrow  = qg + base + (size_t)(wave * 16 + m) * HW + k8;
  const bf16* krow0 = kg + base + (size_t)m * HW + k8;
  f32x4 acc0 = {0.f, 0.f, 0.f, 0.f}, acc1 = acc0, acc2 = acc0, acc3 = acc0;
  for (int kb = 0; kb < CHUNK; kb += 32) {
    int off = chunk * CHUNK + kb;
    frag16 a  = *(const frag16*)(qrow + off);
    frag16 b0 = *(const frag16*)(krow0 + off);
    frag16 b1 = *(const frag16*)(krow0 + (size_t)16 * HW + off);
    frag16 b2 = *(const frag16*)(krow0 + (size_t)32 * HW + off);
    frag16 b3 = *(const frag16*)(krow0 + (size_t)48 * HW + off);
    acc0 = __builtin_amdgcn_mfma_f32_16x16x32_bf16(a, b0, acc0, 0, 0, 0);
    acc1 = __builtin_amdgcn_mfma_f32_16x16x32_bf16(a, b1, acc1, 0, 0, 0);
    acc2 = __builtin_amdgcn_mfma_f32_16x16x32_bf16(a, b2, acc2, 0, 0, 0);
    acc3 = __builtin_amdgcn_mfma_f32_16x16x32_bf16(a, b3, acc3, 0, 0, 0);
  }
  // C/D layout: row(d) = (lane>>4)*4 + r, col(e) = lane&15
  float* po = part + (size_t)(bh * NCH + chunk) * 4096;
  int dr = wave * 16 + (lane >> 4) * 4;
  int e0 = lane & 15;
#pragma unroll
  for (int r = 0; r < 4; ++r) {
    po[(dr + r) * 64 +  0 + e0] = acc0[r];
    po[(dr + r) * 64 + 16 + e0] = acc1[r];
    po[(dr + r) * 64 + 32 + e0] = acc2[r];
    po[(dr + r) * 64 + 48 + e0] = acc3[r];
  }
}

// ---------------------------------------------------------------- K2b: reduce partials + normalize + softmax
// block = bh, 256 threads: thread (d = tid>>2, eq = tid&3) owns 16 e's.
// Reduces 16 chunk-partials in registers, softmaxes row d, emits bf16 hi/lo split.
__global__ __launch_bounds__(256) void k2_softmax(
    const float* __restrict__ part, bf16* __restrict__ ah, bf16* __restrict__ al,
    const float* __restrict__ qn2, const float* __restrict__ kn2,
    const float* __restrict__ t_f) {
  __shared__ float kns[64], qns[64];
  int bh = blockIdx.x, tid = threadIdx.x;
  int d = tid >> 2, eq = tid & 3;
  if (tid < 64)       kns[tid] = fmaxf(sqrtf(kn2[bh * 64 + tid]), 1e-12f);
  else if (tid < 128) qns[tid - 64] = fmaxf(sqrtf(qn2[bh * 64 + tid - 64]), 1e-12f);
  __syncthreads();

  const float* pb = part + (size_t)bh * NCH * 4096;
  int e0 = eq * 16;
  float v[16];
#pragma unroll
  for (int i = 0; i < 4; ++i) {
    float4 s = make_float4(0.f, 0.f, 0.f, 0.f);
#pragma unroll
    for (int ch = 0; ch < NCH; ++ch) {
      float4 g = *(const float4*)&pb[ch * 4096 + d * 64 + e0 + i * 4];
      s.x += g.x; s.y += g.y; s.z += g.z; s.w += g.w;
    }
    v[i * 4 + 0] = s.x; v[i * 4 + 1] = s.y; v[i * 4 + 2] = s.z; v[i * 4 + 3] = s.w;
  }
  float sc = t_f[bh & 7] / qns[d];
  float m = -1e30f;
#pragma unroll
  for (int j = 0; j < 16; ++j) {
    v[j] = v[j] * sc / kns[e0 + j];
    m = fmaxf(m, v[j]);
  }
  m = fmaxf(m, __shfl_xor(m, 1));
  m = fmaxf(m, __shfl_xor(m, 2));
  float s = 0.f;
#pragma unroll
  for (int j = 0; j < 16; ++j) { v[j] = __expf(v[j] - m); s += v[j]; }
  s += __shfl_xor(s, 1);
  s += __shfl_xor(s, 2);
  float inv = 1.f / s;
  const size_t base = (size_t)bh * 4096 + d * 64 + e0;
  unsigned short hi16[16], lo16[16];
#pragma unroll
  for (int j = 0; j < 16; ++j) {
    float p = v[j] * inv;
    bf16 hi = f2b(p);
    float lo = p - b2f(hi);
    bf16 lov = f2b(lo);
    hi16[j] = *(unsigned short*)&hi;
    lo16[j] = *(unsigned short*)&lov;
  }
  *(uint4*)(ah + base)     = *(uint4*)&hi16[0];
  *(uint4*)(ah + base + 8) = *(uint4*)&hi16[8];
  *(uint4*)(al + base)     = *(uint4*)&lo16[0];
  *(uint4*)(al + base + 8) = *(uint4*)&lo16[8];
}

// ---------------------------------------------------------------- K3: o = attn @ v via MFMA
// block = (chunk of 256 px, bh). v tile staged in LDS [64 e][260 pad] bf16.
__global__ __launch_bounds__(256) void k3_av(
    const bf16* __restrict__ ah, const bf16* __restrict__ al,
    const bf16* __restrict__ vg, bf16* __restrict__ og) {
  __shared__ unsigned short vs[64 * 260];   // 33.3 KB
  int tid = threadIdx.x;
  int wave = tid >> 6, lane = tid & 63;
  int chunk = blockIdx.x;   // 0..35 (256 pixels each)
  int bh = blockIdx.y;      // 0..63
  int b = bh >> 3, h = bh & 7;
  int n0 = chunk * 256;
  const bf16* vp = vg + (size_t)bh * HD * HW;
#pragma unroll
  for (int i = 0; i < 16; ++i) {
    int lin = i * 256 + tid;            // ushort4 units: 64 rows * 64 units
    int e = lin >> 6, c4 = lin & 63;
    ushort4 vv = *(const ushort4*)(vp + (size_t)e * HW + n0 + c4 * 4);
    *(ushort4*)&vs[e * 260 + c4 * 4] = vv;
  }
  __syncthreads();

  int m = lane & 15;
  int k8 = (lane >> 4) * 8;
  const bf16* ahp = ah + (size_t)bh * 4096;
  const bf16* alp = al + (size_t)bh * 4096;
  frag16 a_hi[4][2], a_lo[4][2];
#pragma unroll
  for (int dt = 0; dt < 4; ++dt)
#pragma unroll
    for (int kh = 0; kh < 2; ++kh) {
      a_hi[dt][kh] = *(const frag16*)(ahp + (dt * 16 + m) * 64 + kh * 32 + k8);
      a_lo[dt][kh] = *(const frag16*)(alp + (dt * 16 + m) * 64 + kh * 32 + k8);
    }

  f32x4 acc[4][4];
#pragma unroll
  for (int dt = 0; dt < 4; ++dt)
#pragma unroll
    for (int nt = 0; nt < 4; ++nt) acc[dt][nt] = {0.f, 0.f, 0.f, 0.f};

  int nwbase = wave * 64;
#pragma unroll
  for (int nt = 0; nt < 4; ++nt) {
#pragma unroll
    for (int kh = 0; kh < 2; ++kh) {
      frag16 bf;
#pragma unroll
      for (int j = 0; j < 8; ++j)
        bf[j] = (short)vs[(kh * 32 + k8 + j) * 260 + nwbase + nt * 16 + m];
#pragma unroll
      for (int dt = 0; dt < 4; ++dt) {
        acc[dt][nt] = __builtin_amdgcn_mfma_f32_16x16x32_bf16(a_hi[dt][kh], bf, acc[dt][nt], 0, 0, 0);
        acc[dt][nt] = __builtin_amdgcn_mfma_f32_16x16x32_bf16(a_lo[dt][kh], bf, acc[dt][nt], 0, 0, 0);
      }
    }
  }
  int cc0 = (h & 1) * 256 + (h >> 1);
  bf16* ob = og + (size_t)b * 512 * HW;
  int q4 = (lane >> 4) * 4;
#pragma unroll
  for (int dt = 0; dt < 4; ++dt)
#pragma unroll
    for (int nt = 0; nt < 4; ++nt) {
      int n = n0 + nwbase + nt * 16 + m;
#pragma unroll
      for (int r = 0; r < 4; ++r) {
        int d = dt * 16 + q4 + r;
        ob[(size_t)(cc0 + d * 4) * HW + n] = f2b(acc[dt][nt][r]);
      }
    }
}

// ---------------------------------------------------------------- K4: fused grouped 3x3 conv (4 in-ch -> 1 out-ch)
__global__ __launch_bounds__(256) void k4_fuse(
    const bf16* __restrict__ og, const float* __restrict__ wf,
    const float* __restrict__ bfu, float* __restrict__ out) {
  __shared__ float lds[26 * 100 * 4];   // 41.6 KB
  int tid = threadIdx.x;
  int tile = blockIdx.x;                // 0..3
  int bc = blockIdx.y;                  // 0..1023
  int b = bc >> 7, c = bc & 127;
  for (int i = tid; i < (26 * 100 * 4) / 4; i += 256)
    ((float4*)lds)[i] = make_float4(0.f, 0.f, 0.f, 0.f);
  __syncthreads();
  int r0 = tile * 24 - 1;
  const bf16* op = og + (size_t)(b * 512 + c * 4) * HW;
  for (int i = tid; i < 26 * 96; i += 256) {
    int rr = i / 96, x = i - rr * 96;
    int gr = r0 + rr;
    if (gr >= 0 && gr < 96) {
      int gp = gr * 96 + x;
      float4 vv;
      vv.x = b2f(op[gp]);
      vv.y = b2f(op[HW + gp]);
      vv.z = b2f(op[2 * HW + gp]);
      vv.w = b2f(op[(size_t)3 * HW + gp]);
      *(float4*)&lds[(rr * 100 + 2 + x) * 4] = vv;
    }
  }
  __syncthreads();
  const float* wrow = wf + c * 36;      // uniform -> s_load
  float bias = bfu[c];
  float* outp = out + (size_t)(b * CC + c) * HW + tile * 24 * 96;
#pragma unroll
  for (int pi = 0; pi < 9; ++pi) {
    int p = pi * 256 + tid;
    int ry = p / 96, x = p - ry * 96;
    float a0 = bias, a1 = 0.f, a2 = 0.f, a3 = 0.f;
#pragma unroll
    for (int ky = 0; ky < 3; ++ky)
#pragma unroll
      for (int kx = 0; kx < 3; ++kx) {
        const float4 vv = *(const float4*)&lds[((ry + ky) * 100 + 1 + x + kx) * 4];
        a0 = fmaf(wrow[0 + ky * 3 + kx],  vv.x, a0);
        a1 = fmaf(wrow[9 + ky * 3 + kx],  vv.y, a1);
        a2 = fmaf(wrow[18 + ky * 3 + kx], vv.z, a2);
        a3 = fmaf(wrow[27 + ky * 3 + kx], vv.w, a3);
      }
    outp[p] = (a0 + a1) + (a2 + a3);
  }
}

// ---------------------------------------------------------------- launcher
extern "C" void kernel_launch(void* const* d_in, const int* in_sizes, int n_in,
                              void* d_out, int out_size, void* d_ws, size_t ws_size,
                              hipStream_t stream) {
  (void)in_sizes; (void)n_in; (void)out_size; (void)ws_size;
  const float* x   = (const float*)d_in[0];
  const float* wq  = (const float*)d_in[1];
  const float* bq  = (const float*)d_in[2];
  const float* tt  = (const float*)d_in[3];
  const float* wf  = (const float*)d_in[4];
  const float* bfu = (const float*)d_in[5];

  // workspace layout (~245 MB)
  char* ws = (char*)d_ws;
  bf16*  qg    = (bf16*)(ws + 0);                 // 75497472 B, later aliased by og
  bf16*  kg    = (bf16*)(ws + 75497472);          // 75497472 B
  bf16*  vg    = (bf16*)(ws + 150994944);         // 75497472 B
  float* part  = (float*)(ws + 226492416);        // 16777216 B
  bf16*  ah    = (bf16*)(ws + 243269632);         // 524288 B
  bf16*  al    = (bf16*)(ws + 243793920);         // 524288 B
  float* qn2   = (float*)(ws + 244318208);        // 16384 B
  float* kn2   = (float*)(ws + 244334592);        // 16384 B
  bf16*  og    = qg;                              // q is dead after k2_gram
  float* out   = (float*)d_out;

  hipLaunchKernelGGL(k1_qkv, dim3(1024), dim3(256), 0, stream,
                     x, wq, bq, qg, kg, vg, qn2, kn2);
  hipLaunchKernelGGL(k2_gram, dim3(NCH, 64), dim3(256), 0, stream, qg, kg, part);
  hipLaunchKernelGGL(k2_softmax, dim3(64), dim3(256), 0, stream,
                     part, ah, al, qn2, kn2, tt);
  hipLaunchKernelGGL(k3_av, dim3(36, 64), dim3(256), 0, stream, ah, al, vg, og);
  hipLaunchKernelGGL(k4_fuse, dim3(4, 1024), dim3(256), 0, stream, og, wf, bfu, out);
}